// Round 8
// baseline (184.900 us; speedup 1.0000x reference)
//
#include <hip/hip_runtime.h>
#include <hip/hip_bf16.h>

#define NEG_SLOPE 0.2f

constexpr int B = 4, LQ = 1024, LK = 1024, D = 512, H = 8, HD = 64;

typedef __attribute__((ext_vector_type(8))) short bf16x8;
typedef __attribute__((ext_vector_type(4))) float f32x4;

static __device__ __forceinline__ ushort f2bf(float x) {
  return __builtin_bit_cast(ushort, __float2bfloat16(x));
}
static __device__ __forceinline__ float bf2f(ushort u) {
  return __bfloat162float(__builtin_bit_cast(__hip_bfloat16, u));
}

// ---------------------------------------------------------------------------
// Kernel 1: w_q[h][j] = sum_d a[0,h,d] * W[h*HD+d][j]; w_k likewise with a_k.
// ---------------------------------------------------------------------------
__global__ void prep_wqwk(const float* __restrict__ W, const float* __restrict__ a,
                          float* __restrict__ wq, float* __restrict__ wk) {
  int tid = blockIdx.x * blockDim.x + threadIdx.x;  // 0..4095
  int h = tid >> 9, j = tid & 511;
  const float* aq = a + h * 2 * HD;
  const float* ak = aq + HD;
  float accq = 0.f, acck = 0.f;
#pragma unroll 8
  for (int d = 0; d < HD; ++d) {
    float w = W[(size_t)(h * HD + d) * D + j];
    accq = fmaf(aq[d], w, accq);
    acck = fmaf(ak[d], w, acck);
  }
  wq[tid] = accq;
  wk[tid] = acck;
}

// ---------------------------------------------------------------------------
// Kernel 2 (fused): blocks [0,2304): cvt_split value/W -> bf16 hi/lo
//                   blocks [2304,4352): bit-pack mask (8 rows per wave)
//                   blocks [4352,6400): sqsk row-dot products (needs wq/wk)
// ---------------------------------------------------------------------------
__global__ __launch_bounds__(256) void fused_aux(
    const float* __restrict__ query, const float* __restrict__ key,
    const float* __restrict__ value, const int* __restrict__ mask,
    const float* __restrict__ W,
    const float* __restrict__ wq, const float* __restrict__ wk,
    ushort* __restrict__ val_hi, ushort* __restrict__ val_lo,
    ushort* __restrict__ w_hi, ushort* __restrict__ w_lo,
    unsigned int* __restrict__ mbits,
    float* __restrict__ sq, float* __restrict__ sk) {
  int blk = blockIdx.x, tid = threadIdx.x;
  if (blk < 2304) {
    // ---- cvt_split: idx in [0, 589824) covers VAL4+W4 exactly ----
    constexpr int VAL4 = B * LK * D / 4;  // 524288
    int idx = blk * 256 + tid;
    const float* src;
    ushort *dhi, *dlo;
    int off;
    if (idx < VAL4) { src = value; dhi = val_hi; dlo = val_lo; off = idx; }
    else           { src = W;     dhi = w_hi;   dlo = w_lo;   off = idx - VAL4; }
    float4 x = ((const float4*)src)[off];
    float xs[4] = {x.x, x.y, x.z, x.w};
    ushort hs[4], ls[4];
#pragma unroll
    for (int i = 0; i < 4; ++i) {
      hs[i] = f2bf(xs[i]);
      ls[i] = f2bf(xs[i] - bf2f(hs[i]));
    }
    ((ushort4*)dhi)[off] = make_ushort4(hs[0], hs[1], hs[2], hs[3]);
    ((ushort4*)dlo)[off] = make_ushort4(ls[0], ls[1], ls[2], ls[3]);
  } else if (blk < 4352) {
    // ---- maskbits: 8192 waves, 8 contiguous 64-wide rows each ----
    int gw = ((blk - 2304) * 256 + tid) >> 6;  // 0..8191
    int lane = tid & 63;
#pragma unroll
    for (int it = 0; it < 8; ++it) {
      int wv = gw * 8 + it;  // 0..65535
      int mv = mask[(size_t)wv * 64 + lane];
      unsigned long long bal = __ballot(mv != 0);
      if (lane == 0) *(unsigned long long*)&mbits[wv * 2] = bal;
    }
  } else {
    // ---- sqsk: one wave per row ----
    int gw = ((blk - 4352) * 256 + tid) >> 6;  // 0..8191
    int lane = tid & 63;
    bool isK = gw >= B * LQ;
    int row = isK ? gw - B * LQ : gw;
    const float* x = (isK ? key : query) + (size_t)row * D + lane * 8;
    const float* wbase = isK ? wk : wq;
    float4 x0 = *(const float4*)x;
    float4 x1 = *(const float4*)(x + 4);
    float acc[H];
#pragma unroll
    for (int h = 0; h < H; ++h) {
      const float* w = wbase + h * D + lane * 8;
      float4 w0 = *(const float4*)w;
      float4 w1 = *(const float4*)(w + 4);
      acc[h] = x0.x * w0.x + x0.y * w0.y + x0.z * w0.z + x0.w * w0.w +
               x1.x * w1.x + x1.y * w1.y + x1.z * w1.z + x1.w * w1.w;
    }
#pragma unroll
    for (int off = 32; off > 0; off >>= 1) {
#pragma unroll
      for (int h = 0; h < H; ++h) acc[h] += __shfl_xor(acc[h], off, 64);
    }
    if (lane == 0) {
      int b = row >> 10, pos = row & 1023;
      float* dst = isK ? sk : sq;
#pragma unroll
      for (int h = 0; h < H; ++h) dst[((size_t)(b * H + h) << 10) + pos] = acc[h];
    }
  }
}

// ---------------------------------------------------------------------------
// Kernel 3: V = value @ W.T via split-bf16 MFMA (3-term), writing transposed
// bf16 hi/lo: vt[(b*H+h)*64+dd][k].
// No-LDS main loop: A/B fragments read directly from L2 (value tile 128KB,
// W 1MB — both L2-resident). 4 waves = K-split x4 (128 K each); merge via LDS.
// Per wave: 64x32 output tile (4 m-frags x 2 n-frags), MFMA-bound.
// grid (D/32, M/64) so consecutive blocks share the value row-tile in L2.
// ---------------------------------------------------------------------------
__global__ __launch_bounds__(256) void vproj_mfma(
    const ushort* __restrict__ val_hi, const ushort* __restrict__ val_lo,
    const ushort* __restrict__ w_hi, const ushort* __restrict__ w_lo,
    ushort* __restrict__ vt_hi, ushort* __restrict__ vt_lo) {
  __shared__ float vred[3][64][36];  // [khalf-1][lane][32 acc + pad] = 27.6KB
  int c0 = blockIdx.x * 32, r0 = blockIdx.y * 64;
  int tid = threadIdx.x, w = tid >> 6, lane = tid & 63;
  int ln15 = lane & 15, kg = lane >> 4;
  f32x4 acc[4][2] = {};
  for (int step = 0; step < 4; ++step) {
    int kq = w * 128 + step * 32 + kg * 8;
    bf16x8 ah[4], al[4], bh[2], bl[2];
#pragma unroll
    for (int fm = 0; fm < 4; ++fm) {
      size_t off = (size_t)(r0 + fm * 16 + ln15) * D + kq;
      ah[fm] = *(const bf16x8*)&val_hi[off];
      al[fm] = *(const bf16x8*)&val_lo[off];
    }
#pragma unroll
    for (int fn = 0; fn < 2; ++fn) {
      size_t off = (size_t)(c0 + fn * 16 + ln15) * D + kq;
      bh[fn] = *(const bf16x8*)&w_hi[off];
      bl[fn] = *(const bf16x8*)&w_lo[off];
    }
#pragma unroll
    for (int fm = 0; fm < 4; ++fm)
#pragma unroll
      for (int fn = 0; fn < 2; ++fn) {
        acc[fm][fn] = __builtin_amdgcn_mfma_f32_16x16x32_bf16(ah[fm], bh[fn], acc[fm][fn], 0, 0, 0);
        acc[fm][fn] = __builtin_amdgcn_mfma_f32_16x16x32_bf16(al[fm], bh[fn], acc[fm][fn], 0, 0, 0);
        acc[fm][fn] = __builtin_amdgcn_mfma_f32_16x16x32_bf16(ah[fm], bl[fn], acc[fm][fn], 0, 0, 0);
      }
  }
  if (w > 0) {
#pragma unroll
    for (int fm = 0; fm < 4; ++fm)
#pragma unroll
      for (int fn = 0; fn < 2; ++fn)
        *(f32x4*)&vred[w - 1][lane][(fm * 2 + fn) * 4] = acc[fm][fn];
  }
  __syncthreads();
  if (w == 0) {
#pragma unroll
    for (int fm = 0; fm < 4; ++fm)
#pragma unroll
      for (int fn = 0; fn < 2; ++fn) {
#pragma unroll
        for (int k = 0; k < 3; ++k)
          acc[fm][fn] += *(const f32x4*)&vred[k][lane][(fm * 2 + fn) * 4];
        int rrow = r0 + fm * 16 + (lane >> 4) * 4;  // 4 consecutive k of vt
        int col = c0 + fn * 16 + ln15;
        int bb = rrow >> 10, kk = rrow & 1023;
        int hh = col >> 6, dd = col & 63;
        size_t base = ((size_t)((bb * H + hh) * HD + dd) << 10) + kk;
        ushort hv[4], lv[4];
#pragma unroll
        for (int r = 0; r < 4; ++r) {
          float v = acc[fm][fn][r];
          hv[r] = f2bf(v);
          lv[r] = f2bf(v - bf2f(hv[r]));
        }
        *(ushort4*)&vt_hi[base] = make_ushort4(hv[0], hv[1], hv[2], hv[3]);
        *(ushort4*)&vt_lo[base] = make_ushort4(lv[0], lv[1], lv[2], lv[3]);
      }
  }
}

// ---------------------------------------------------------------------------
// Kernel 4: attention. 1024 blocks (XCD-swizzled: each XCD owns 4 bh -> 1MB
// of V in its L2). Block = 32 q-rows; 4 waves = 2 q-strips x 2 k-halves.
// V fragments read directly from L2 (no LDS staging, no main-loop barriers).
// K-split halves merged via LDS at the end (constant-shift softmax => partial
// accs/lsums add directly).
// ---------------------------------------------------------------------------
__global__ __launch_bounds__(256) void attn_mfma(
    const float* __restrict__ sq, const float* __restrict__ sk,
    const unsigned int* __restrict__ mbits,
    const ushort* __restrict__ vt_hi, const ushort* __restrict__ vt_lo,
    float* __restrict__ out) {
  __shared__ float sks[LK];
  __shared__ float ared[2][64][36];  // [strip][lane][16 acc + pad] = 18KB
  __shared__ float lred[2][16];
  __shared__ float linv_s[2][16];
  int bid = blockIdx.x;
  int xcd = bid & 7, slot = bid >> 3;
  int bh = xcd * 4 + (slot & 3), qt = slot >> 2;  // bh 0..31, qt 0..31
  int b = bh >> 3, h = bh & 7;
  int q0 = qt * 32;
  int tid = threadIdx.x, w = tid >> 6, lane = tid & 63;
  int strip = w & 1, khalf = w >> 1;
  int ln15 = lane & 15, kg = lane >> 4;
  int qs = q0 + strip * 16 + ln15;  // this lane's q row (A-frag m index)
#pragma unroll
  for (int i = 0; i < 4; ++i) sks[i * 256 + tid] = sk[((size_t)bh << 10) + i * 256 + tid];
  float sqv = sq[((size_t)bh << 10) + qs];
  const unsigned int* mrow = mbits + ((size_t)(b << 10) + qs) * (LK / 32);
  const ushort* vhbase = vt_hi + (((size_t)bh * HD) << 10);
  const ushort* vlbase = vt_lo + (((size_t)bh * HD) << 10);
  __syncthreads();
  f32x4 acc[4] = {};
  float lsum = 0.f;
  for (int tile = 0; tile < 4; ++tile) {
    int kt0 = khalf * 512 + tile * 128;
#pragma unroll
    for (int ks = 0; ks < 4; ++ks) {
      int kb = kt0 + ks * 32;
      unsigned int wb = mrow[kb >> 5];
      bf16x8 bhv[4], blv[4];
#pragma unroll
      for (int df = 0; df < 4; ++df) {
        size_t off = ((size_t)(df * 16 + ln15) << 10) + kb + kg * 8;
        bhv[df] = *(const bf16x8*)&vhbase[off];
        blv[df] = *(const bf16x8*)&vlbase[off];
      }
      float skv[8];
      *(float4*)&skv[0] = *(const float4*)&sks[kb + kg * 8];
      *(float4*)&skv[4] = *(const float4*)&sks[kb + kg * 8 + 4];
      bf16x8 phi, plo;
#pragma unroll
      for (int i = 0; i < 8; ++i) {
        float s = sqv + skv[i];
        float f = fmaxf(s, NEG_SLOPE * s);
        float p = ((wb >> (kg * 8 + i)) & 1u) ? __expf(f - 8.0f) : 0.f;
        lsum += p;
        ushort hb = f2bf(p);
        phi[i] = (short)hb;
        plo[i] = (short)f2bf(p - bf2f(hb));
      }
#pragma unroll
      for (int df = 0; df < 4; ++df) {
        acc[df] = __builtin_amdgcn_mfma_f32_16x16x32_bf16(phi, bhv[df], acc[df], 0, 0, 0);
        acc[df] = __builtin_amdgcn_mfma_f32_16x16x32_bf16(plo, bhv[df], acc[df], 0, 0, 0);
        acc[df] = __builtin_amdgcn_mfma_f32_16x16x32_bf16(phi, blv[df], acc[df], 0, 0, 0);
      }
    }
  }
  lsum += __shfl_xor(lsum, 16, 64);
  lsum += __shfl_xor(lsum, 32, 64);
  if (khalf == 1) {
#pragma unroll
    for (int df = 0; df < 4; ++df)
      *(f32x4*)&ared[strip][lane][df * 4] = acc[df];
    if (lane < 16) lred[strip][lane] = lsum;
  }
  __syncthreads();
  if (khalf == 0) {
#pragma unroll
    for (int df = 0; df < 4; ++df)
      acc[df] += *(const f32x4*)&ared[strip][lane][df * 4];
    lsum += lred[strip][ln15];
    if (lane < 16) linv_s[strip][lane] = (lsum > 0.f) ? 1.f / lsum : 0.f;
    // wave-internal LDS write->read (same wave, program order): no barrier
#pragma unroll
    for (int df = 0; df < 4; ++df) {
#pragma unroll
      for (int r = 0; r < 4; ++r) {
        int crow = (lane >> 4) * 4 + r;  // verified C layout (m89)
        int qrow = q0 + strip * 16 + crow;
        float inv = linv_s[strip][crow];
        int col = h * HD + df * 16 + ln15;
        out[((size_t)(b << 10) + qrow) * D + col] = acc[df][r] * inv;
      }
    }
  }
}

// ---------------------------------------------------------------------------
extern "C" void kernel_launch(void* const* d_in, const int* in_sizes, int n_in,
                              void* d_out, int out_size, void* d_ws, size_t ws_size,
                              hipStream_t stream) {
  const float* query = (const float*)d_in[0];
  const float* key   = (const float*)d_in[1];
  const float* value = (const float*)d_in[2];
  const int*   mask  = (const int*)d_in[3];
  const float* W     = (const float*)d_in[4];
  const float* a     = (const float*)d_in[5];
  float* out = (float*)d_out;

  char* ws = (char*)d_ws;
  float* wq = (float*)ws;                    ws += 4096 * 4;
  float* wk = (float*)ws;                    ws += 4096 * 4;
  float* sq = (float*)ws;                    ws += 32768 * 4;
  float* sk = (float*)ws;                    ws += 32768 * 4;
  ushort* val_hi = (ushort*)ws;              ws += (size_t)B * LK * D * 2;
  ushort* val_lo = (ushort*)ws;              ws += (size_t)B * LK * D * 2;
  ushort* w_hi = (ushort*)ws;                ws += (size_t)D * D * 2;
  ushort* w_lo = (ushort*)ws;                ws += (size_t)D * D * 2;
  ushort* vt_hi = (ushort*)ws;               ws += (size_t)B * H * HD * LK * 2;
  ushort* vt_lo = (ushort*)ws;               ws += (size_t)B * H * HD * LK * 2;
  unsigned int* mbits = (unsigned int*)ws;   ws += (size_t)B * LQ * LK / 32 * 4;

  prep_wqwk<<<dim3(16), dim3(256), 0, stream>>>(W, a, wq, wk);
  fused_aux<<<dim3(6400), dim3(256), 0, stream>>>(
      query, key, value, mask, W, wq, wk,
      val_hi, val_lo, w_hi, w_lo, mbits, sq, sk);
  vproj_mfma<<<dim3(D / 32, B * LK / 64), dim3(256), 0, stream>>>(
      val_hi, val_lo, w_hi, w_lo, vt_hi, vt_lo);
  attn_mfma<<<dim3(32 * LQ / 32), dim3(256), 0, stream>>>(
      sq, sk, mbits, vt_hi, vt_lo, out);
}

// Round 11
// 169.484 us; speedup vs baseline: 1.0910x; 1.0910x over previous
//
#include <hip/hip_runtime.h>
#include <hip/hip_bf16.h>

#define NEG_SLOPE 0.2f

constexpr int B = 4, LQ = 1024, LK = 1024, D = 512, H = 8, HD = 64;

typedef __attribute__((ext_vector_type(8))) short bf16x8;
typedef __attribute__((ext_vector_type(4))) float f32x4;

static __device__ __forceinline__ ushort f2bf(float x) {
  return __builtin_bit_cast(ushort, __float2bfloat16(x));
}
static __device__ __forceinline__ float bf2f(ushort u) {
  return __bfloat162float(__builtin_bit_cast(__hip_bfloat16, u));
}

// ---------------------------------------------------------------------------
// Kernel 1: w_q[h][j] = sum_d a[0,h,d] * W[h*HD+d][j]; w_k likewise with a_k.
// ---------------------------------------------------------------------------
__global__ void prep_wqwk(const float* __restrict__ W, const float* __restrict__ a,
                          float* __restrict__ wq, float* __restrict__ wk) {
  int tid = blockIdx.x * blockDim.x + threadIdx.x;  // 0..4095
  int h = tid >> 9, j = tid & 511;
  const float* aq = a + h * 2 * HD;
  const float* ak = aq + HD;
  float accq = 0.f, acck = 0.f;
#pragma unroll 8
  for (int d = 0; d < HD; ++d) {
    float w = W[(size_t)(h * HD + d) * D + j];
    accq = fmaf(aq[d], w, accq);
    acck = fmaf(ak[d], w, acck);
  }
  wq[tid] = accq;
  wk[tid] = acck;
}

// ---------------------------------------------------------------------------
// Kernel 2 (fused): blocks [0,2304): cvt_split value/W -> bf16 hi/lo
//                   blocks [2304,4352): bit-pack mask (8 rows per wave)
//                   blocks [4352,6400): sqsk row-dot products (needs wq/wk)
// ---------------------------------------------------------------------------
__global__ __launch_bounds__(256) void fused_aux(
    const float* __restrict__ query, const float* __restrict__ key,
    const float* __restrict__ value, const int* __restrict__ mask,
    const float* __restrict__ W,
    const float* __restrict__ wq, const float* __restrict__ wk,
    ushort* __restrict__ val_hi, ushort* __restrict__ val_lo,
    ushort* __restrict__ w_hi, ushort* __restrict__ w_lo,
    unsigned int* __restrict__ mbits,
    float* __restrict__ sq, float* __restrict__ sk) {
  int blk = blockIdx.x, tid = threadIdx.x;
  if (blk < 2304) {
    constexpr int VAL4 = B * LK * D / 4;  // 524288
    int idx = blk * 256 + tid;
    const float* src;
    ushort *dhi, *dlo;
    int off;
    if (idx < VAL4) { src = value; dhi = val_hi; dlo = val_lo; off = idx; }
    else           { src = W;     dhi = w_hi;   dlo = w_lo;   off = idx - VAL4; }
    float4 x = ((const float4*)src)[off];
    float xs[4] = {x.x, x.y, x.z, x.w};
    ushort hs[4], ls[4];
#pragma unroll
    for (int i = 0; i < 4; ++i) {
      hs[i] = f2bf(xs[i]);
      ls[i] = f2bf(xs[i] - bf2f(hs[i]));
    }
    ((ushort4*)dhi)[off] = make_ushort4(hs[0], hs[1], hs[2], hs[3]);
    ((ushort4*)dlo)[off] = make_ushort4(ls[0], ls[1], ls[2], ls[3]);
  } else if (blk < 4352) {
    int gw = ((blk - 2304) * 256 + tid) >> 6;  // 0..8191
    int lane = tid & 63;
#pragma unroll
    for (int it = 0; it < 8; ++it) {
      int wv = gw * 8 + it;  // 0..65535
      int mv = mask[(size_t)wv * 64 + lane];
      unsigned long long bal = __ballot(mv != 0);
      if (lane == 0) *(unsigned long long*)&mbits[wv * 2] = bal;
    }
  } else {
    int gw = ((blk - 4352) * 256 + tid) >> 6;  // 0..8191
    int lane = tid & 63;
    bool isK = gw >= B * LQ;
    int row = isK ? gw - B * LQ : gw;
    const float* x = (isK ? key : query) + (size_t)row * D + lane * 8;
    const float* wbase = isK ? wk : wq;
    float4 x0 = *(const float4*)x;
    float4 x1 = *(const float4*)(x + 4);
    float acc[H];
#pragma unroll
    for (int h = 0; h < H; ++h) {
      const float* w = wbase + h * D + lane * 8;
      float4 w0 = *(const float4*)w;
      float4 w1 = *(const float4*)(w + 4);
      acc[h] = x0.x * w0.x + x0.y * w0.y + x0.z * w0.z + x0.w * w0.w +
               x1.x * w1.x + x1.y * w1.y + x1.z * w1.z + x1.w * w1.w;
    }
#pragma unroll
    for (int off = 32; off > 0; off >>= 1) {
#pragma unroll
      for (int h = 0; h < H; ++h) acc[h] += __shfl_xor(acc[h], off, 64);
    }
    if (lane == 0) {
      int b = row >> 10, pos = row & 1023;
      float* dst = isK ? sk : sq;
#pragma unroll
      for (int h = 0; h < H; ++h) dst[((size_t)(b * H + h) << 10) + pos] = acc[h];
    }
  }
}

// ---------------------------------------------------------------------------
// Kernel 3: V = value @ W.T via split-bf16 MFMA (3-term), writing transposed
// bf16 hi/lo: vt[(b*H+h)*64+dd][k].  64x64 tile, BK=64, classic 2-phase LDS
// (regs load -> bar -> LDS store -> bar -> compute). 4 waves = 2x2 of 32x32.
// ---------------------------------------------------------------------------
__global__ __launch_bounds__(256) void vproj_mfma(
    const ushort* __restrict__ val_hi, const ushort* __restrict__ val_lo,
    const ushort* __restrict__ w_hi, const ushort* __restrict__ w_lo,
    ushort* __restrict__ vt_hi, ushort* __restrict__ vt_lo) {
  __shared__ ushort as_hi[64][72], as_lo[64][72], bs_hi[64][72], bs_lo[64][72];
  int r0 = blockIdx.x * 64, c0 = blockIdx.y * 64;
  int tid = threadIdx.x, w = tid >> 6, lane = tid & 63;
  int wr = w >> 1, wc = w & 1;
  int ln15 = lane & 15, kg = lane >> 4;
  f32x4 acc[2][2] = {};
  int srow = tid >> 2, scol = (tid & 3) * 16;
  const size_t arow = (size_t)(r0 + srow) * D;
  const size_t brow = (size_t)(c0 + srow) * D;
  for (int k0 = 0; k0 < D; k0 += 64) {
    float4 ra0 = *(const float4*)&val_hi[arow + k0 + scol];
    float4 ra1 = *(const float4*)&val_hi[arow + k0 + scol + 8];
    float4 rb0 = *(const float4*)&val_lo[arow + k0 + scol];
    float4 rb1 = *(const float4*)&val_lo[arow + k0 + scol + 8];
    float4 rc0 = *(const float4*)&w_hi[brow + k0 + scol];
    float4 rc1 = *(const float4*)&w_hi[brow + k0 + scol + 8];
    float4 rd0 = *(const float4*)&w_lo[brow + k0 + scol];
    float4 rd1 = *(const float4*)&w_lo[brow + k0 + scol + 8];
    __syncthreads();  // previous compute done before overwrite
    *(float4*)&as_hi[srow][scol] = ra0; *(float4*)&as_hi[srow][scol + 8] = ra1;
    *(float4*)&as_lo[srow][scol] = rb0; *(float4*)&as_lo[srow][scol + 8] = rb1;
    *(float4*)&bs_hi[srow][scol] = rc0; *(float4*)&bs_hi[srow][scol + 8] = rc1;
    *(float4*)&bs_lo[srow][scol] = rd0; *(float4*)&bs_lo[srow][scol + 8] = rd1;
    __syncthreads();
#pragma unroll
    for (int ks2 = 0; ks2 < 2; ++ks2) {
      bf16x8 ah[2], al[2], bh[2], bl[2];
#pragma unroll
      for (int f = 0; f < 2; ++f) {
        int ra = wr * 32 + f * 16 + ln15;
        ah[f] = *(const bf16x8*)&as_hi[ra][ks2 * 32 + kg * 8];
        al[f] = *(const bf16x8*)&as_lo[ra][ks2 * 32 + kg * 8];
        int rb = wc * 32 + f * 16 + ln15;
        bh[f] = *(const bf16x8*)&bs_hi[rb][ks2 * 32 + kg * 8];
        bl[f] = *(const bf16x8*)&bs_lo[rb][ks2 * 32 + kg * 8];
      }
#pragma unroll
      for (int fm = 0; fm < 2; ++fm)
#pragma unroll
        for (int fn = 0; fn < 2; ++fn) {
          acc[fm][fn] = __builtin_amdgcn_mfma_f32_16x16x32_bf16(ah[fm], bh[fn], acc[fm][fn], 0, 0, 0);
          acc[fm][fn] = __builtin_amdgcn_mfma_f32_16x16x32_bf16(al[fm], bh[fn], acc[fm][fn], 0, 0, 0);
          acc[fm][fn] = __builtin_amdgcn_mfma_f32_16x16x32_bf16(ah[fm], bl[fn], acc[fm][fn], 0, 0, 0);
        }
    }
  }
#pragma unroll
  for (int fm = 0; fm < 2; ++fm)
#pragma unroll
    for (int fn = 0; fn < 2; ++fn) {
      int rrow = r0 + wr * 32 + fm * 16 + (lane >> 4) * 4;  // 4 consecutive k
      int col = c0 + wc * 32 + fn * 16 + ln15;
      int bb = rrow >> 10, kk = rrow & 1023;
      int hh = col >> 6, dd = col & 63;
      size_t base = ((size_t)((bb * H + hh) * HD + dd) << 10) + kk;
      ushort hv[4], lv[4];
#pragma unroll
      for (int r = 0; r < 4; ++r) {
        float v = acc[fm][fn][r];
        hv[r] = f2bf(v);
        lv[r] = f2bf(v - bf2f(hv[r]));
      }
      *(ushort4*)&vt_hi[base] = make_ushort4(hv[0], hv[1], hv[2], hv[3]);
      *(ushort4*)&vt_lo[base] = make_ushort4(lv[0], lv[1], lv[2], lv[3]);
    }
}

// ---------------------------------------------------------------------------
// Kernel 4: attention. 1024 blocks (XCD-swizzled); 4 waves = 2 q-strips x
// 2 k-halves. Factored exp: exp(leaky(sq+sk)) = max(e^s, e^.2s); row-scale
// invariance drops the per-q factor: p' = max(skE, rq*skF), rq = e^(-0.8 sq),
// skE/skF precomputed in LDS. lsum via ones-column MFMA (acc5) => softmax is
// exactly consistent with the bf16-rounded P (plo term dropped). Mask words
// preloaded to regs. V (hi+lo) fragments straight from L2.
// ---------------------------------------------------------------------------
__global__ __launch_bounds__(256) void attn_mfma(
    const float* __restrict__ sq, const float* __restrict__ sk,
    const unsigned int* __restrict__ mbits,
    const ushort* __restrict__ vt_hi, const ushort* __restrict__ vt_lo,
    float* __restrict__ out) {
  __shared__ float skE_s[LK], skF_s[LK];
  __shared__ float ared[2][64][24];  // 20 used, pad to 24
  int bid = blockIdx.x;
  int xcd = bid & 7, slot = bid >> 3;
  int bh = xcd * 4 + (slot & 3), qt = slot >> 2;  // bh 0..31, qt 0..31
  int b = bh >> 3, h = bh & 7;
  int q0 = qt * 32;
  int tid = threadIdx.x, w = tid >> 6, lane = tid & 63;
  int strip = w & 1, khalf = w >> 1;
  int ln15 = lane & 15, kg = lane >> 4;
  int qs = q0 + strip * 16 + ln15;
#pragma unroll
  for (int i = 0; i < 4; ++i) {
    int j = i * 256 + tid;
    float skv = sk[((size_t)bh << 10) + j];
    skE_s[j] = __expf(skv - 4.0f);
    skF_s[j] = __expf(0.2f * skv - 4.0f);
  }
  float sqv = sq[((size_t)bh << 10) + qs];
  float rq = __expf(-0.8f * sqv);
  const uint4* mrowp = (const uint4*)(mbits + ((size_t)(b << 10) + qs) * (LK / 32) + khalf * 16);
  uint4 mw0 = mrowp[0], mw1 = mrowp[1], mw2 = mrowp[2], mw3 = mrowp[3];
  const ushort* vhbase = vt_hi + (((size_t)bh * HD) << 10);
  const ushort* vlbase = vt_lo + (((size_t)bh * HD) << 10);
  bf16x8 ones;
#pragma unroll
  for (int i = 0; i < 8; ++i) ones[i] = (short)0x3F80;  // bf16 1.0
  __syncthreads();
  f32x4 acc[4] = {};
  f32x4 acc5 = {};
  unsigned int mwords[16] = {mw0.x, mw0.y, mw0.z, mw0.w, mw1.x, mw1.y, mw1.z, mw1.w,
                             mw2.x, mw2.y, mw2.z, mw2.w, mw3.x, mw3.y, mw3.z, mw3.w};
#pragma unroll
  for (int t = 0; t < 16; ++t) {  // fully unrolled: mwords[t] static
    int kb = khalf * 512 + t * 32;
    unsigned int wb = mwords[t];
    bf16x8 bhv[4], blv[4];
#pragma unroll
    for (int df = 0; df < 4; ++df) {
      size_t off = ((size_t)(df * 16 + ln15) << 10) + kb + kg * 8;
      bhv[df] = *(const bf16x8*)&vhbase[off];
      blv[df] = *(const bf16x8*)&vlbase[off];
    }
    float ev[8], fv[8];
    *(float4*)&ev[0] = *(const float4*)&skE_s[kb + kg * 8];
    *(float4*)&ev[4] = *(const float4*)&skE_s[kb + kg * 8 + 4];
    *(float4*)&fv[0] = *(const float4*)&skF_s[kb + kg * 8];
    *(float4*)&fv[4] = *(const float4*)&skF_s[kb + kg * 8 + 4];
    bf16x8 phi;
#pragma unroll
    for (int i = 0; i < 8; ++i) {
      float pf = fmaxf(ev[i], rq * fv[i]);  // = exp(leaky(s))/qE
      float p = ((wb >> (kg * 8 + i)) & 1u) ? pf : 0.f;
      phi[i] = (short)f2bf(p);
    }
#pragma unroll
    for (int df = 0; df < 4; ++df) {
      acc[df] = __builtin_amdgcn_mfma_f32_16x16x32_bf16(phi, bhv[df], acc[df], 0, 0, 0);
      acc[df] = __builtin_amdgcn_mfma_f32_16x16x32_bf16(phi, blv[df], acc[df], 0, 0, 0);
    }
    acc5 = __builtin_amdgcn_mfma_f32_16x16x32_bf16(phi, ones, acc5, 0, 0, 0);
  }
  if (khalf == 1) {
#pragma unroll
    for (int df = 0; df < 4; ++df)
      *(f32x4*)&ared[strip][lane][df * 4] = acc[df];
    *(f32x4*)&ared[strip][lane][16] = acc5;
  }
  __syncthreads();
  if (khalf == 0) {
#pragma unroll
    for (int df = 0; df < 4; ++df)
      acc[df] += *(const f32x4*)&ared[strip][lane][df * 4];
    acc5 += *(const f32x4*)&ared[strip][lane][16];
    float inv[4];
#pragma unroll
    for (int r = 0; r < 4; ++r) inv[r] = (acc5[r] > 0.f) ? 1.f / acc5[r] : 0.f;
#pragma unroll
    for (int df = 0; df < 4; ++df) {
#pragma unroll
      for (int r = 0; r < 4; ++r) {
        int crow = (lane >> 4) * 4 + r;  // verified C layout (m89)
        int qrow = q0 + strip * 16 + crow;
        int col = h * HD + df * 16 + ln15;
        out[((size_t)(b << 10) + qrow) * D + col] = acc[df][r] * inv[r];
      }
    }
  }
}

// ---------------------------------------------------------------------------
extern "C" void kernel_launch(void* const* d_in, const int* in_sizes, int n_in,
                              void* d_out, int out_size, void* d_ws, size_t ws_size,
                              hipStream_t stream) {
  const float* query = (const float*)d_in[0];
  const float* key   = (const float*)d_in[1];
  const float* value = (const float*)d_in[2];
  const int*   mask  = (const int*)d_in[3];
  const float* W     = (const float*)d_in[4];
  const float* a     = (const float*)d_in[5];
  float* out = (float*)d_out;

  char* ws = (char*)d_ws;
  float* wq = (float*)ws;                    ws += 4096 * 4;
  float* wk = (float*)ws;                    ws += 4096 * 4;
  float* sq = (float*)ws;                    ws += 32768 * 4;
  float* sk = (float*)ws;                    ws += 32768 * 4;
  ushort* val_hi = (ushort*)ws;              ws += (size_t)B * LK * D * 2;
  ushort* val_lo = (ushort*)ws;              ws += (size_t)B * LK * D * 2;
  ushort* w_hi = (ushort*)ws;                ws += (size_t)D * D * 2;
  ushort* w_lo = (ushort*)ws;                ws += (size_t)D * D * 2;
  ushort* vt_hi = (ushort*)ws;               ws += (size_t)B * H * HD * LK * 2;
  ushort* vt_lo = (ushort*)ws;               ws += (size_t)B * H * HD * LK * 2;
  unsigned int* mbits = (unsigned int*)ws;   ws += (size_t)B * LQ * LK / 32 * 4;

  prep_wqwk<<<dim3(16), dim3(256), 0, stream>>>(W, a, wq, wk);
  fused_aux<<<dim3(6400), dim3(256), 0, stream>>>(
      query, key, value, mask, W, wq, wk,
      val_hi, val_lo, w_hi, w_lo, mbits, sq, sk);
  vproj_mfma<<<dim3(B * LK / 64, D / 64), dim3(256), 0, stream>>>(
      val_hi, val_lo, w_hi, w_lo, vt_hi, vt_lo);
  attn_mfma<<<dim3(32 * LQ / 32), dim3(256), 0, stream>>>(
      sq, sk, mbits, vt_hi, vt_lo, out);
}